// Round 2
// baseline (950.078 us; speedup 1.0000x reference)
//
#include <hip/hip_runtime.h>

// Problem constants: B=4, De=Do=64, T=4, H=W=128, PATCH=7, R=3
#define ATTN_OFF 4194304                 // B*Do*H*W (mem region size in floats)
// packed attn ws: [b][G=256][t][13][64] float4  = 3,407,872 float4s
#define WS_F4_COUNT 3407872ull

// ---------------------------------------------------------------------------
// K1 v3: correlation logits.
//  - 2 vertical pixels per thread (tile 32x16), 8-row shared window.
//  - staging: per-item = one pixel x 4 consecutive channels. 4 coalesced
//    dword loads + ONE ds_write_b128 at consecutive-16B addresses across
//    lanes -> conflict-free (R1 had 8-way write conflicts, 7.6M cycles).
//  - double-buffered LDS with register-staged prefetch: global loads for
//    chunk cc+1 are issued BEFORE the compute of chunk cc, written to the
//    alternate buffer after the barrier -> HBM latency hides under compute.
//  - channel summation order unchanged -> numerics identical.
// ---------------------------------------------------------------------------
__global__ __launch_bounds__(256, 2) void k1_corr(
    const float* __restrict__ m_in, const float* __restrict__ q_in,
    float* __restrict__ out)
{
  const int b = blockIdx.z >> 2, t = blockIdx.z & 3;
  const int h0 = blockIdx.y * 16, w0 = blockIdx.x * 32;
  const int tid = threadIdx.x;
  const int tx = tid & 31, ty = tid >> 5;

  // [buf][c-quad][y 0..21][x 0..41][c%4]; x index xi+1 <-> gx = w0-3+xi
  __shared__ float m_s[2][2][22][42][4];   // 59,136 B

  float acc0[49], acc1[49];
#pragma unroll
  for (int d = 0; d < 49; ++d) { acc0[d] = 0.f; acc1[d] = 0.f; }

  float r[7][4];    // in-flight staging registers (1672 items / 256 threads)

  // 1672 items = 2 quads x 22 rows x 38 xi
  auto k1_load = [&](int cc) {
    const float* base = m_in + (((b * 64 + cc * 8) * 4 + t) << 14);
#pragma unroll
    for (int k = 0; k < 7; ++k) {
      const int item = tid + 256 * k;
      r[k][0] = 0.f; r[k][1] = 0.f; r[k][2] = 0.f; r[k][3] = 0.f;
      if (item < 1672) {
        const int quad = item >= 836;
        const int rem  = item - 836 * quad;
        const int y  = rem / 38;             // magic-mul
        const int xi = rem - 38 * y;
        const int gy = h0 - 3 + y, gx = w0 - 3 + xi;
        if ((unsigned)gy < 128u && (unsigned)gx < 128u) {
          const float* p = base + (quad << 18) + (gy << 7) + gx;
          r[k][0] = p[0];
          r[k][1] = p[1 << 16];
          r[k][2] = p[2 << 16];
          r[k][3] = p[3 << 16];
        }
      }
    }
  };

  auto k1_write = [&](int buf) {
#pragma unroll
    for (int k = 0; k < 7; ++k) {
      const int item = tid + 256 * k;
      if (item < 1672) {
        const int quad = item >= 836;
        const int rem  = item - 836 * quad;
        const int y  = rem / 38;
        const int xi = rem - 38 * y;
        *(float4*)&m_s[buf][quad][y][xi + 1][0] =
            make_float4(r[k][0], r[k][1], r[k][2], r[k][3]);
      }
    }
  };

  auto k1_compute = [&](int cc, int buf) {
#pragma unroll
    for (int cq = 0; cq < 2; ++cq) {
      float q0[4], q1[4];
#pragma unroll
      for (int k = 0; k < 4; ++k) {
        const float* qp = q_in + ((b * 64 + cc * 8 + cq * 4 + k) << 14)
                        + ((h0 + 2 * ty) << 7) + w0 + tx;
        q0[k] = qp[0];
        q1[k] = qp[128];
      }
#pragma unroll
      for (int wr = 0; wr < 8; ++wr) {      // shared 8-row window, 2 pixels
        const float4* rowp = (const float4*)&m_s[buf][cq][2 * ty + wr][tx + 1][0];
#pragma unroll
        for (int dx = 0; dx < 7; ++dx) {
          const float4 mv = rowp[dx];
          if (wr < 7)
            acc0[wr * 7 + dx] += q0[0]*mv.x + q0[1]*mv.y + q0[2]*mv.z + q0[3]*mv.w;
          if (wr > 0)
            acc1[(wr - 1) * 7 + dx] += q1[0]*mv.x + q1[1]*mv.y + q1[2]*mv.z + q1[3]*mv.w;
        }
      }
    }
  };

  // prologue: stage chunk 0 into buf 0
  k1_load(0);
  k1_write(0);
  __syncthreads();

#pragma unroll 1
  for (int cc = 0; cc < 8; ++cc) {          // 8-channel chunks
    const int buf = cc & 1;
    if (cc < 7) k1_load(cc + 1);            // issue early: hides under compute
    k1_compute(cc, buf);
    __syncthreads();                        // all waves done reading buf^1
    if (cc < 7) k1_write(buf ^ 1);
    __syncthreads();                        // buf^1 visible for next iter
  }

  const int obase = ATTN_OFF + ((b * 196 + t) << 14)
                  + ((h0 + 2 * ty) << 7) + w0 + tx;
#pragma unroll
  for (int d = 0; d < 49; ++d) {
    out[obase +       ((d * 4) << 14)] = acc0[d];
    out[obase + 128 + ((d * 4) << 14)] = acc1[d];
  }
}

// ---------------------------------------------------------------------------
// K2: softmax (unchanged) + packed-attn write into d_ws.
// Packed layout keyed to k3's wave tiling: G = (h>>1)*4 + (w>>5),
// lane = (h&1)*32 + (w&31); element (b,G,t,g,lane) at
// ((b*256+G)*4+t)*13*64 + g*64 + lane   (float4 units, d = 4g+j).
// ---------------------------------------------------------------------------
__global__ __launch_bounds__(256) void k2_softmax(
    float* __restrict__ out, const float* __restrict__ cst,
    float4* __restrict__ ws)
{
  const int tid = threadIdx.x;
  const int pl = tid & 63;             // pixel within block
  const int t  = tid >> 6;
  const int pix = blockIdx.x * 64 + pl;      // 65536 pixels total
  const int b = pix >> 14, hw = pix & 16383;
  float* base = out + ATTN_OFF + ((b * 196 + t) << 14) + hw;

  float v[49];
#pragma unroll
  for (int d = 0; d < 49; ++d) v[d] = base[(d * 4) << 14];

  float mx = -1e30f;
#pragma unroll
  for (int d = 0; d < 49; ++d) mx = fmaxf(mx, v[d]);

  __shared__ float red[4][64];
  red[t][pl] = mx;
  __syncthreads();
  float M = fmaxf(fmaxf(red[0][pl], red[1][pl]), fmaxf(red[2][pl], red[3][pl]));
  M = fmaxf(M, cst[0]);
  __syncthreads();

  float s = 0.f;
#pragma unroll
  for (int d = 0; d < 49; ++d) { v[d] = __expf(v[d] - M); s += v[d]; }
  red[t][pl] = s;
  __syncthreads();
  const float l = red[0][pl] + red[1][pl] + red[2][pl] + red[3][pl]
                + __expf(cst[0] - M);
  const float inv = 1.f / l;
#pragma unroll
  for (int d = 0; d < 49; ++d) {
    const float r = v[d] * inv;
    base[(d * 4) << 14] = r;           // reference-layout output (validated)
    v[d] = r;
  }

  if (ws) {
    const int h = hw >> 7, wc = hw & 127;
    const int G    = ((h >> 1) << 2) + (wc >> 5);
    const int lane = ((h & 1) << 5) + (wc & 31);
    float4* dst = ws + (size_t)(((b * 256 + G) * 4 + t) * 13) * 64 + lane;
#pragma unroll
    for (int g = 0; g < 13; ++g) {
      float4 p;
      p.x = v[g * 4];
      p.y = (g < 12) ? v[g * 4 + 1] : 0.f;
      p.z = (g < 12) ? v[g * 4 + 2] : 0.f;
      p.w = (g < 12) ? v[g * 4 + 3] : 0.f;
      dst[g * 64] = p;
    }
  }
}

// ---------------------------------------------------------------------------
// K3 (packed-ws variant): attn read as 13 coalesced dwordx4 per (thread,t),
// 1-deep software pipeline. Staging switched to per-pixel channel-quad
// items: 4 coalesced dword loads + one conflict-free ds_write_b128
// (same fix as k1). Tiling and ws layout unchanged.
// ---------------------------------------------------------------------------
__global__ __launch_bounds__(256) void k3_read_ws(
    const float* __restrict__ m_out, float* __restrict__ out,
    const float4* __restrict__ ws)
{
  const int b = blockIdx.z >> 2, cq = blockIdx.z & 3;
  const int h0 = blockIdx.y * 8, w0 = blockIdx.x * 32;
  const int tid = threadIdx.x;
  const int tx = tid & 31, ty = tid >> 5;
  const int h = h0 + ty, w = w0 + tx;
  const int waveid = tid >> 6, lane = tid & 63;
  const int G = ((h0 >> 1) + waveid) * 4 + blockIdx.x;

  __shared__ float m_s[4][14][42][4];  // 37,632 B

  float acc[16];
#pragma unroll
  for (int i = 0; i < 16; ++i) acc[i] = 0.f;

#pragma unroll 1
  for (int t = 0; t < 4; ++t) {
    const float4* ap = ws + (size_t)(((b * 256 + G) * 4 + t) * 13) * 64 + lane;

    __syncthreads();
    {
      // 2128 items = 4 quads x 14 rows x 38 xi
      const float* base = m_out + (((b * 64 + cq * 16) * 4 + t) << 14);
#pragma unroll
      for (int k = 0; k < 9; ++k) {
        const int item = tid + 256 * k;
        if (item < 2128) {
          const int quad = item / 532;       // 532 = 14*38
          const int rem  = item - 532 * quad;
          const int y  = rem / 38;
          const int xi = rem - 38 * y;
          const int gy = h0 - 3 + y, gx = w0 - 3 + xi;
          float4 v = make_float4(0.f, 0.f, 0.f, 0.f);
          if ((unsigned)gy < 128u && (unsigned)gx < 128u) {
            const float* p = base + (quad << 18) + (gy << 7) + gx;
            v.x = p[0];
            v.y = p[1 << 16];
            v.z = p[2 << 16];
            v.w = p[3 << 16];
          }
          *(float4*)&m_s[quad][y][xi + 1][0] = v;
        }
      }
    }
    __syncthreads();

    float4 cur = ap[0];
#pragma unroll
    for (int g = 0; g < 13; ++g) {
      float4 nxt = cur;
      if (g < 12) nxt = ap[(g + 1) * 64];
#pragma unroll
      for (int j = 0; j < 4; ++j) {
        const int d = g * 4 + j;
        if (d >= 49) break;
        const int dy = d / 7, dx = d % 7;
        const float av = (j == 0) ? cur.x : (j == 1) ? cur.y
                       : (j == 2) ? cur.z : cur.w;
#pragma unroll
        for (int q = 0; q < 4; ++q) {
          const float4 mv = *(const float4*)&m_s[q][ty + dy][tx + dx + 1][0];
          acc[q * 4 + 0] += av * mv.x;
          acc[q * 4 + 1] += av * mv.y;
          acc[q * 4 + 2] += av * mv.z;
          acc[q * 4 + 3] += av * mv.w;
        }
      }
      cur = nxt;
    }
  }

#pragma unroll
  for (int q = 0; q < 4; ++q)
#pragma unroll
    for (int k = 0; k < 4; ++k)
      out[((b * 64 + cq * 16 + q * 4 + k) << 14) + (h << 7) + w] = acc[q * 4 + k];
}

// ---------------------------------------------------------------------------
// K3 fallback (unchanged) — used only if ws_size is too small.
// ---------------------------------------------------------------------------
__global__ __launch_bounds__(256) void k3_read_fb(
    const float* __restrict__ m_out, float* __restrict__ out)
{
  const int b = blockIdx.z >> 2, cq = blockIdx.z & 3;
  const int h0 = blockIdx.y * 8, w0 = blockIdx.x * 32;
  const int tid = threadIdx.x;
  const int tx = tid & 31, ty = tid >> 5;
  const int h = h0 + ty, w = w0 + tx;

  __shared__ float m_s[4][14][38][4];
  const float* __restrict__ attn = out + ATTN_OFF;

  float acc[16];
#pragma unroll
  for (int i = 0; i < 16; ++i) acc[i] = 0.f;

#pragma unroll 1
  for (int t = 0; t < 4; ++t) {
    float a[49];
#pragma unroll
    for (int d = 0; d < 49; ++d)
      a[d] = attn[((b * 196 + d * 4 + t) << 14) + (h << 7) + w];

    __syncthreads();
    for (int e = tid; e < 8512; e += 256) {
      int c16 = e / 532; int rem = e - c16 * 532;
      int y = rem / 38;  int x = rem - y * 38;
      int gy = h0 - 3 + y, gx = w0 - 3 + x;
      float v = 0.f;
      if (gy >= 0 && gy < 128 && gx >= 0 && gx < 128)
        v = m_out[(((b * 64 + cq * 16 + c16) * 4 + t) << 14) + (gy << 7) + gx];
      m_s[c16 >> 2][y][x][c16 & 3] = v;
    }
    __syncthreads();

#pragma unroll
    for (int dy = 0; dy < 7; ++dy)
#pragma unroll
      for (int dx = 0; dx < 7; ++dx) {
        const float av = a[dy * 7 + dx];
#pragma unroll
        for (int q = 0; q < 4; ++q) {
          const float4 mv = *(const float4*)&m_s[q][ty + dy][tx + dx][0];
          acc[q * 4 + 0] += av * mv.x;
          acc[q * 4 + 1] += av * mv.y;
          acc[q * 4 + 2] += av * mv.z;
          acc[q * 4 + 3] += av * mv.w;
        }
      }
  }

#pragma unroll
  for (int q = 0; q < 4; ++q)
#pragma unroll
    for (int k = 0; k < 4; ++k)
      out[((b * 64 + cq * 16 + q * 4 + k) << 14) + (h << 7) + w] = acc[q * 4 + k];
}

extern "C" void kernel_launch(void* const* d_in, const int* in_sizes, int n_in,
                              void* d_out, int out_size, void* d_ws, size_t ws_size,
                              hipStream_t stream) {
  const float* m_in  = (const float*)d_in[0];
  const float* m_out = (const float*)d_in[1];
  const float* q_in  = (const float*)d_in[2];
  const float* cst   = (const float*)d_in[3];
  float* out = (float*)d_out;

  const bool use_ws = (ws_size >= WS_F4_COUNT * 16ull) && d_ws != nullptr;
  float4* ws = use_ws ? (float4*)d_ws : nullptr;

  k1_corr<<<dim3(4, 8, 16), dim3(256), 0, stream>>>(m_in, q_in, out);
  k2_softmax<<<dim3(1024), dim3(256), 0, stream>>>(out, cst, ws);
  if (use_ws)
    k3_read_ws<<<dim3(4, 16, 16), dim3(256), 0, stream>>>(m_out, out, ws);
  else
    k3_read_fb<<<dim3(4, 16, 16), dim3(256), 0, stream>>>(m_out, out);
}

// Round 3
// 197.174 us; speedup vs baseline: 4.8185x; 4.8185x over previous
//
#include <hip/hip_runtime.h>

// Problem constants: B=4, De=Do=64, T=4, H=W=128, PATCH=7, R=3
#define ATTN_OFF 4194304                 // B*Do*H*W (mem region size in floats)
// packed attn ws: [b][G=256][t][13][64] float4  = 3,407,872 float4s
#define WS_F4_COUNT 3407872ull

// ---------------------------------------------------------------------------
// K1 v4: correlation logits.
//  - R1 structure: 2 vertical pixels/thread (tile 32x16), 8-row shared
//    window, SINGLE buffer, no cross-chunk register carry (R2's r[7][4]
//    carry spilled acc to scratch: 1.6 GB writes).
//  - staging: per-item = one pixel x 4 consecutive channels. 4 coalesced
//    dword loads + ONE ds_write_b128 immediately (transient regs only).
//    Conflict-free writes (R2 verified: 7.6M -> 135K conflict cycles).
//  - channel summation order unchanged -> numerics identical.
// ---------------------------------------------------------------------------
__global__ __launch_bounds__(256, 2) void k1_corr(
    const float* __restrict__ m_in, const float* __restrict__ q_in,
    float* __restrict__ out)
{
  const int b = blockIdx.z >> 2, t = blockIdx.z & 3;
  const int h0 = blockIdx.y * 16, w0 = blockIdx.x * 32;
  const int tid = threadIdx.x;
  const int tx = tid & 31, ty = tid >> 5;

  // [c-quad][y 0..21][x 0..41][c%4]; slot xi+1 <-> gx = w0-3+xi
  __shared__ float m_s[2][22][42][4];   // 29,568 B

  float acc0[49], acc1[49];
#pragma unroll
  for (int d = 0; d < 49; ++d) { acc0[d] = 0.f; acc1[d] = 0.f; }

#pragma unroll 1
  for (int cc = 0; cc < 8; ++cc) {          // 8-channel chunks
    __syncthreads();                        // prev chunk's reads complete
    {
      // 1672 items = 2 quads x 22 rows x 38 xi ; load -> immediate b128 write
      const float* base = m_in + (((b * 64 + cc * 8) * 4 + t) << 14);
#pragma unroll
      for (int k = 0; k < 7; ++k) {
        const int item = tid + (k << 8);
        if (item < 1672) {
          const int quad = item >= 836;
          const int rem  = item - 836 * quad;
          const int y  = rem / 38;             // magic-mul
          const int xi = rem - 38 * y;
          const int gy = h0 - 3 + y, gx = w0 - 3 + xi;
          float4 v = make_float4(0.f, 0.f, 0.f, 0.f);
          if ((unsigned)gy < 128u && (unsigned)gx < 128u) {
            const float* p = base + (quad << 18) + (gy << 7) + gx;
            v.x = p[0];
            v.y = p[1 << 16];
            v.z = p[2 << 16];
            v.w = p[3 << 16];
          }
          *(float4*)&m_s[quad][y][xi + 1][0] = v;
        }
      }
    }
    __syncthreads();

#pragma unroll
    for (int cq = 0; cq < 2; ++cq) {
      float q0[4], q1[4];
#pragma unroll
      for (int k = 0; k < 4; ++k) {
        const float* qp = q_in + ((b * 64 + cc * 8 + cq * 4 + k) << 14)
                        + ((h0 + 2 * ty) << 7) + w0 + tx;
        q0[k] = qp[0];
        q1[k] = qp[128];
      }
#pragma unroll
      for (int wr = 0; wr < 8; ++wr) {      // shared 8-row window, 2 pixels
        const float4* rowp = (const float4*)&m_s[cq][2 * ty + wr][tx + 1][0];
#pragma unroll
        for (int dx = 0; dx < 7; ++dx) {
          const float4 mv = rowp[dx];
          if (wr < 7)
            acc0[wr * 7 + dx] += q0[0]*mv.x + q0[1]*mv.y + q0[2]*mv.z + q0[3]*mv.w;
          if (wr > 0)
            acc1[(wr - 1) * 7 + dx] += q1[0]*mv.x + q1[1]*mv.y + q1[2]*mv.z + q1[3]*mv.w;
        }
      }
    }
  }

  const int obase = ATTN_OFF + ((b * 196 + t) << 14)
                  + ((h0 + 2 * ty) << 7) + w0 + tx;
#pragma unroll
  for (int d = 0; d < 49; ++d) {
    out[obase +       ((d * 4) << 14)] = acc0[d];
    out[obase + 128 + ((d * 4) << 14)] = acc1[d];
  }
}

// ---------------------------------------------------------------------------
// K2: softmax (unchanged) + packed-attn write into d_ws.
// Packed layout keyed to k3's wave tiling: G = (h>>1)*4 + (w>>5),
// lane = (h&1)*32 + (w&31); element (b,G,t,g,lane) at
// ((b*256+G)*4+t)*13*64 + g*64 + lane   (float4 units, d = 4g+j).
// ---------------------------------------------------------------------------
__global__ __launch_bounds__(256) void k2_softmax(
    float* __restrict__ out, const float* __restrict__ cst,
    float4* __restrict__ ws)
{
  const int tid = threadIdx.x;
  const int pl = tid & 63;             // pixel within block
  const int t  = tid >> 6;
  const int pix = blockIdx.x * 64 + pl;      // 65536 pixels total
  const int b = pix >> 14, hw = pix & 16383;
  float* base = out + ATTN_OFF + ((b * 196 + t) << 14) + hw;

  float v[49];
#pragma unroll
  for (int d = 0; d < 49; ++d) v[d] = base[(d * 4) << 14];

  float mx = -1e30f;
#pragma unroll
  for (int d = 0; d < 49; ++d) mx = fmaxf(mx, v[d]);

  __shared__ float red[4][64];
  red[t][pl] = mx;
  __syncthreads();
  float M = fmaxf(fmaxf(red[0][pl], red[1][pl]), fmaxf(red[2][pl], red[3][pl]));
  M = fmaxf(M, cst[0]);
  __syncthreads();

  float s = 0.f;
#pragma unroll
  for (int d = 0; d < 49; ++d) { v[d] = __expf(v[d] - M); s += v[d]; }
  red[t][pl] = s;
  __syncthreads();
  const float l = red[0][pl] + red[1][pl] + red[2][pl] + red[3][pl]
                + __expf(cst[0] - M);
  const float inv = 1.f / l;
#pragma unroll
  for (int d = 0; d < 49; ++d) {
    const float r = v[d] * inv;
    base[(d * 4) << 14] = r;           // reference-layout output (validated)
    v[d] = r;
  }

  if (ws) {
    const int h = hw >> 7, wc = hw & 127;
    const int G    = ((h >> 1) << 2) + (wc >> 5);
    const int lane = ((h & 1) << 5) + (wc & 31);
    float4* dst = ws + (size_t)(((b * 256 + G) * 4 + t) * 13) * 64 + lane;
#pragma unroll
    for (int g = 0; g < 13; ++g) {
      float4 p;
      p.x = v[g * 4];
      p.y = (g < 12) ? v[g * 4 + 1] : 0.f;
      p.z = (g < 12) ? v[g * 4 + 2] : 0.f;
      p.w = (g < 12) ? v[g * 4 + 3] : 0.f;
      dst[g * 64] = p;
    }
  }
}

// ---------------------------------------------------------------------------
// K3 v3 (packed-ws): 2 vertical pixels/thread (tile 32x16), 8-row shared
// window -> ds_read_b128 per pixel*t drops 196 -> 112 (1.75x LDS cut).
// Both pixels of a thread live in the SAME ws group G (lanes tx and tx+32).
// Attn for both pixels unpacked to 98 statically-indexed scalars before the
// FMA loop. launch_bounds(256,1): VGPR budget 512 -> no spill (LDS caps
// occupancy at 2 blocks/CU regardless).
// ---------------------------------------------------------------------------
__global__ __launch_bounds__(256, 1) void k3_read_ws(
    const float* __restrict__ m_out, float* __restrict__ out,
    const float4* __restrict__ ws)
{
  const int b = blockIdx.z >> 2, cq = blockIdx.z & 3;
  const int h0 = blockIdx.y * 16, w0 = blockIdx.x * 32;
  const int tid = threadIdx.x;
  const int tx = tid & 31, ty = tid >> 5;      // ty 0..7
  const int G = ((h0 >> 1) + ty) * 4 + blockIdx.x;

  __shared__ float m_s[4][22][42][4];  // 59,136 B

  float acc0[16], acc1[16];
#pragma unroll
  for (int i = 0; i < 16; ++i) { acc0[i] = 0.f; acc1[i] = 0.f; }

#pragma unroll 1
  for (int t = 0; t < 4; ++t) {
    const float4* ap = ws + (size_t)(((b * 256 + G) * 4 + t) * 13) * 64;

    __syncthreads();                   // prev iter's reads complete
    {
      // 3344 items = 4 quads x 22 rows x 38 xi ; load -> immediate b128 write
      const float* base = m_out + (((b * 64 + cq * 16) * 4 + t) << 14);
#pragma unroll
      for (int k = 0; k < 14; ++k) {
        const int item = tid + (k << 8);
        if (item < 3344) {
          const int quad = item / 836;       // 836 = 22*38
          const int rem  = item - 836 * quad;
          const int y  = rem / 38;
          const int xi = rem - 38 * y;
          const int gy = h0 - 3 + y, gx = w0 - 3 + xi;
          float4 v = make_float4(0.f, 0.f, 0.f, 0.f);
          if ((unsigned)gy < 128u && (unsigned)gx < 128u) {
            const float* p = base + (quad << 18) + (gy << 7) + gx;
            v.x = p[0];
            v.y = p[1 << 16];
            v.z = p[2 << 16];
            v.w = p[3 << 16];
          }
          *(float4*)&m_s[quad][y][xi + 1][0] = v;
        }
      }
    }

    // attn for both pixels (independent of LDS) — issue before the barrier
    float av0[49], av1[49];
#pragma unroll
    for (int g = 0; g < 13; ++g) {
      const float4 a0 = ap[g * 64 + tx];
      const float4 a1 = ap[g * 64 + 32 + tx];
      av0[g * 4] = a0.x;
      av1[g * 4] = a1.x;
      if (g < 12) {
        av0[g * 4 + 1] = a0.y; av0[g * 4 + 2] = a0.z; av0[g * 4 + 3] = a0.w;
        av1[g * 4 + 1] = a1.y; av1[g * 4 + 2] = a1.z; av1[g * 4 + 3] = a1.w;
      }
    }
    __syncthreads();

#pragma unroll
    for (int wr = 0; wr < 8; ++wr) {         // shared 8-row window
#pragma unroll
      for (int dx = 0; dx < 7; ++dx) {
#pragma unroll
        for (int q = 0; q < 4; ++q) {
          const float4 mv = *(const float4*)&m_s[q][2 * ty + wr][tx + 1 + dx][0];
          if (wr < 7) {
            const float a = av0[wr * 7 + dx];
            acc0[q * 4 + 0] += a * mv.x;
            acc0[q * 4 + 1] += a * mv.y;
            acc0[q * 4 + 2] += a * mv.z;
            acc0[q * 4 + 3] += a * mv.w;
          }
          if (wr > 0) {
            const float a = av1[(wr - 1) * 7 + dx];
            acc1[q * 4 + 0] += a * mv.x;
            acc1[q * 4 + 1] += a * mv.y;
            acc1[q * 4 + 2] += a * mv.z;
            acc1[q * 4 + 3] += a * mv.w;
          }
        }
      }
    }
  }

  const int ob = ((b * 64 + cq * 16) << 14) + ((h0 + 2 * ty) << 7) + w0 + tx;
#pragma unroll
  for (int c = 0; c < 16; ++c) {
    out[ob +       (c << 14)] = acc0[c];
    out[ob + 128 + (c << 14)] = acc1[c];
  }
}

// ---------------------------------------------------------------------------
// K3 fallback (unchanged) — used only if ws_size is too small.
// ---------------------------------------------------------------------------
__global__ __launch_bounds__(256) void k3_read_fb(
    const float* __restrict__ m_out, float* __restrict__ out)
{
  const int b = blockIdx.z >> 2, cq = blockIdx.z & 3;
  const int h0 = blockIdx.y * 8, w0 = blockIdx.x * 32;
  const int tid = threadIdx.x;
  const int tx = tid & 31, ty = tid >> 5;
  const int h = h0 + ty, w = w0 + tx;

  __shared__ float m_s[4][14][38][4];
  const float* __restrict__ attn = out + ATTN_OFF;

  float acc[16];
#pragma unroll
  for (int i = 0; i < 16; ++i) acc[i] = 0.f;

#pragma unroll 1
  for (int t = 0; t < 4; ++t) {
    float a[49];
#pragma unroll
    for (int d = 0; d < 49; ++d)
      a[d] = attn[((b * 196 + d * 4 + t) << 14) + (h << 7) + w];

    __syncthreads();
    for (int e = tid; e < 8512; e += 256) {
      int c16 = e / 532; int rem = e - c16 * 532;
      int y = rem / 38;  int x = rem - y * 38;
      int gy = h0 - 3 + y, gx = w0 - 3 + x;
      float v = 0.f;
      if (gy >= 0 && gy < 128 && gx >= 0 && gx < 128)
        v = m_out[(((b * 64 + cq * 16 + c16) * 4 + t) << 14) + (gy << 7) + gx];
      m_s[c16 >> 2][y][x][c16 & 3] = v;
    }
    __syncthreads();

#pragma unroll
    for (int dy = 0; dy < 7; ++dy)
#pragma unroll
      for (int dx = 0; dx < 7; ++dx) {
        const float av = a[dy * 7 + dx];
#pragma unroll
        for (int q = 0; q < 4; ++q) {
          const float4 mv = *(const float4*)&m_s[q][ty + dy][tx + dx][0];
          acc[q * 4 + 0] += av * mv.x;
          acc[q * 4 + 1] += av * mv.y;
          acc[q * 4 + 2] += av * mv.z;
          acc[q * 4 + 3] += av * mv.w;
        }
      }
  }

#pragma unroll
  for (int q = 0; q < 4; ++q)
#pragma unroll
    for (int k = 0; k < 4; ++k)
      out[((b * 64 + cq * 16 + q * 4 + k) << 14) + (h << 7) + w] = acc[q * 4 + k];
}

extern "C" void kernel_launch(void* const* d_in, const int* in_sizes, int n_in,
                              void* d_out, int out_size, void* d_ws, size_t ws_size,
                              hipStream_t stream) {
  const float* m_in  = (const float*)d_in[0];
  const float* m_out = (const float*)d_in[1];
  const float* q_in  = (const float*)d_in[2];
  const float* cst   = (const float*)d_in[3];
  float* out = (float*)d_out;

  const bool use_ws = (ws_size >= WS_F4_COUNT * 16ull) && d_ws != nullptr;
  float4* ws = use_ws ? (float4*)d_ws : nullptr;

  k1_corr<<<dim3(4, 8, 16), dim3(256), 0, stream>>>(m_in, q_in, out);
  k2_softmax<<<dim3(1024), dim3(256), 0, stream>>>(out, cst, ws);
  if (use_ws)
    k3_read_ws<<<dim3(4, 8, 16), dim3(256), 0, stream>>>(m_out, out, ws);
  else
    k3_read_fb<<<dim3(4, 16, 16), dim3(256), 0, stream>>>(m_out, out);
}

// Round 4
// 180.683 us; speedup vs baseline: 5.2583x; 1.0913x over previous
//
#include <hip/hip_runtime.h>

// Problem constants: B=4, De=Do=64, T=4, H=W=128, PATCH=7, R=3
#define ATTN_OFF 4194304                 // B*Do*H*W (mem region size in floats)
// packed attn ws: [b][G=256][t][13][64] float4  = 3,407,872 float4s
#define WS_F4_COUNT 3407872ull

// ---------------------------------------------------------------------------
// K1 v4 (FROZEN, ~49 us): correlation logits.
//  - 2 vertical pixels/thread (tile 32x16), 8-row shared window, single
//    buffer, no cross-chunk register carry.
//  - staging: per-item = one pixel x 4 consecutive channels. 4 coalesced
//    dword loads + ONE ds_write_b128 immediately. Conflict-free.
// ---------------------------------------------------------------------------
__global__ __launch_bounds__(256, 2) void k1_corr(
    const float* __restrict__ m_in, const float* __restrict__ q_in,
    float* __restrict__ out)
{
  const int b = blockIdx.z >> 2, t = blockIdx.z & 3;
  const int h0 = blockIdx.y * 16, w0 = blockIdx.x * 32;
  const int tid = threadIdx.x;
  const int tx = tid & 31, ty = tid >> 5;

  // [c-quad][y 0..21][x 0..41][c%4]; slot xi+1 <-> gx = w0-3+xi
  __shared__ float m_s[2][22][42][4];   // 29,568 B

  float acc0[49], acc1[49];
#pragma unroll
  for (int d = 0; d < 49; ++d) { acc0[d] = 0.f; acc1[d] = 0.f; }

#pragma unroll 1
  for (int cc = 0; cc < 8; ++cc) {          // 8-channel chunks
    __syncthreads();                        // prev chunk's reads complete
    {
      // 1672 items = 2 quads x 22 rows x 38 xi ; load -> immediate b128 write
      const float* base = m_in + (((b * 64 + cc * 8) * 4 + t) << 14);
#pragma unroll
      for (int k = 0; k < 7; ++k) {
        const int item = tid + (k << 8);
        if (item < 1672) {
          const int quad = item >= 836;
          const int rem  = item - 836 * quad;
          const int y  = rem / 38;             // magic-mul
          const int xi = rem - 38 * y;
          const int gy = h0 - 3 + y, gx = w0 - 3 + xi;
          float4 v = make_float4(0.f, 0.f, 0.f, 0.f);
          if ((unsigned)gy < 128u && (unsigned)gx < 128u) {
            const float* p = base + (quad << 18) + (gy << 7) + gx;
            v.x = p[0];
            v.y = p[1 << 16];
            v.z = p[2 << 16];
            v.w = p[3 << 16];
          }
          *(float4*)&m_s[quad][y][xi + 1][0] = v;
        }
      }
    }
    __syncthreads();

#pragma unroll
    for (int cq = 0; cq < 2; ++cq) {
      float q0[4], q1[4];
#pragma unroll
      for (int k = 0; k < 4; ++k) {
        const float* qp = q_in + ((b * 64 + cc * 8 + cq * 4 + k) << 14)
                        + ((h0 + 2 * ty) << 7) + w0 + tx;
        q0[k] = qp[0];
        q1[k] = qp[128];
      }
#pragma unroll
      for (int wr = 0; wr < 8; ++wr) {      // shared 8-row window, 2 pixels
        const float4* rowp = (const float4*)&m_s[cq][2 * ty + wr][tx + 1][0];
#pragma unroll
        for (int dx = 0; dx < 7; ++dx) {
          const float4 mv = rowp[dx];
          if (wr < 7)
            acc0[wr * 7 + dx] += q0[0]*mv.x + q0[1]*mv.y + q0[2]*mv.z + q0[3]*mv.w;
          if (wr > 0)
            acc1[(wr - 1) * 7 + dx] += q1[0]*mv.x + q1[1]*mv.y + q1[2]*mv.z + q1[3]*mv.w;
        }
      }
    }
  }

  const int obase = ATTN_OFF + ((b * 196 + t) << 14)
                  + ((h0 + 2 * ty) << 7) + w0 + tx;
#pragma unroll
  for (int d = 0; d < 49; ++d) {
    out[obase +       ((d * 4) << 14)] = acc0[d];
    out[obase + 128 + ((d * 4) << 14)] = acc1[d];
  }
}

// ---------------------------------------------------------------------------
// K2: softmax (unchanged) + packed-attn write into d_ws.
// Packed layout keyed to k3's wave tiling: G = (h>>1)*4 + (w>>5),
// lane = (h&1)*32 + (w&31); element (b,G,t,g,lane) at
// ((b*256+G)*4+t)*13*64 + g*64 + lane   (float4 units, d = 4g+j).
// ---------------------------------------------------------------------------
__global__ __launch_bounds__(256) void k2_softmax(
    float* __restrict__ out, const float* __restrict__ cst,
    float4* __restrict__ ws)
{
  const int tid = threadIdx.x;
  const int pl = tid & 63;             // pixel within block
  const int t  = tid >> 6;
  const int pix = blockIdx.x * 64 + pl;      // 65536 pixels total
  const int b = pix >> 14, hw = pix & 16383;
  float* base = out + ATTN_OFF + ((b * 196 + t) << 14) + hw;

  float v[49];
#pragma unroll
  for (int d = 0; d < 49; ++d) v[d] = base[(d * 4) << 14];

  float mx = -1e30f;
#pragma unroll
  for (int d = 0; d < 49; ++d) mx = fmaxf(mx, v[d]);

  __shared__ float red[4][64];
  red[t][pl] = mx;
  __syncthreads();
  float M = fmaxf(fmaxf(red[0][pl], red[1][pl]), fmaxf(red[2][pl], red[3][pl]));
  M = fmaxf(M, cst[0]);
  __syncthreads();

  float s = 0.f;
#pragma unroll
  for (int d = 0; d < 49; ++d) { v[d] = __expf(v[d] - M); s += v[d]; }
  red[t][pl] = s;
  __syncthreads();
  const float l = red[0][pl] + red[1][pl] + red[2][pl] + red[3][pl]
                + __expf(cst[0] - M);
  const float inv = 1.f / l;
#pragma unroll
  for (int d = 0; d < 49; ++d) {
    const float r = v[d] * inv;
    base[(d * 4) << 14] = r;           // reference-layout output (validated)
    v[d] = r;
  }

  if (ws) {
    const int h = hw >> 7, wc = hw & 127;
    const int G    = ((h >> 1) << 2) + (wc >> 5);
    const int lane = ((h & 1) << 5) + (wc & 31);
    float4* dst = ws + (size_t)(((b * 256 + G) * 4 + t) * 13) * 64 + lane;
#pragma unroll
    for (int g = 0; g < 13; ++g) {
      float4 p;
      p.x = v[g * 4];
      p.y = (g < 12) ? v[g * 4 + 1] : 0.f;
      p.z = (g < 12) ? v[g * 4 + 2] : 0.f;
      p.w = (g < 12) ? v[g * 4 + 3] : 0.f;
      dst[g * 64] = p;
    }
  }
}

// ---------------------------------------------------------------------------
// K3 v4 (packed-ws): REVERT to the high-occupancy 1-pixel/thread structure
// (tile 32x8, 16 ch/block, 1024 blocks, 37.6 KB LDS -> 4 blocks/CU), keeping
// the two validated fixes: conflict-free immediate-write staging and the
// g-pipelined coalesced ws reads. (R3's 2-pixel variant collapsed occupancy
// to ~1 block/CU and went latency-bound: 116.9 us, VALUBusy 12.7%.)
// ---------------------------------------------------------------------------
__global__ __launch_bounds__(256) void k3_read_ws(
    const float* __restrict__ m_out, float* __restrict__ out,
    const float4* __restrict__ ws)
{
  const int b = blockIdx.z >> 2, cq = blockIdx.z & 3;
  const int h0 = blockIdx.y * 8, w0 = blockIdx.x * 32;
  const int tid = threadIdx.x;
  const int tx = tid & 31, ty = tid >> 5;
  const int h = h0 + ty, w = w0 + tx;
  const int waveid = tid >> 6, lane = tid & 63;
  const int G = ((h0 >> 1) + waveid) * 4 + blockIdx.x;

  __shared__ float m_s[4][14][42][4];  // 37,632 B

  float acc[16];
#pragma unroll
  for (int i = 0; i < 16; ++i) acc[i] = 0.f;

#pragma unroll 1
  for (int t = 0; t < 4; ++t) {
    const float4* ap = ws + (size_t)(((b * 256 + G) * 4 + t) * 13) * 64 + lane;

    __syncthreads();                   // prev iter's reads complete
    {
      // 2128 items = 4 quads x 14 rows x 38 xi ; load -> immediate b128 write
      const float* base = m_out + (((b * 64 + cq * 16) * 4 + t) << 14);
#pragma unroll
      for (int k = 0; k < 9; ++k) {
        const int item = tid + (k << 8);
        if (item < 2128) {
          const int quad = item / 532;       // 532 = 14*38
          const int rem  = item - 532 * quad;
          const int y  = rem / 38;
          const int xi = rem - 38 * y;
          const int gy = h0 - 3 + y, gx = w0 - 3 + xi;
          float4 v = make_float4(0.f, 0.f, 0.f, 0.f);
          if ((unsigned)gy < 128u && (unsigned)gx < 128u) {
            const float* p = base + (quad << 18) + (gy << 7) + gx;
            v.x = p[0];
            v.y = p[1 << 16];
            v.z = p[2 << 16];
            v.w = p[3 << 16];
          }
          *(float4*)&m_s[quad][y][xi + 1][0] = v;
        }
      }
    }
    __syncthreads();

    float4 cur = ap[0];
#pragma unroll
    for (int g = 0; g < 13; ++g) {
      float4 nxt = cur;
      if (g < 12) nxt = ap[(g + 1) * 64];
#pragma unroll
      for (int j = 0; j < 4; ++j) {
        const int d = g * 4 + j;
        if (d >= 49) break;
        const int dy = d / 7, dx = d % 7;
        const float av = (j == 0) ? cur.x : (j == 1) ? cur.y
                       : (j == 2) ? cur.z : cur.w;
#pragma unroll
        for (int q = 0; q < 4; ++q) {
          const float4 mv = *(const float4*)&m_s[q][ty + dy][tx + dx + 1][0];
          acc[q * 4 + 0] += av * mv.x;
          acc[q * 4 + 1] += av * mv.y;
          acc[q * 4 + 2] += av * mv.z;
          acc[q * 4 + 3] += av * mv.w;
        }
      }
      cur = nxt;
    }
  }

#pragma unroll
  for (int q = 0; q < 4; ++q)
#pragma unroll
    for (int k = 0; k < 4; ++k)
      out[((b * 64 + cq * 16 + q * 4 + k) << 14) + (h << 7) + w] = acc[q * 4 + k];
}

// ---------------------------------------------------------------------------
// K3 fallback (unchanged) — used only if ws_size is too small.
// ---------------------------------------------------------------------------
__global__ __launch_bounds__(256) void k3_read_fb(
    const float* __restrict__ m_out, float* __restrict__ out)
{
  const int b = blockIdx.z >> 2, cq = blockIdx.z & 3;
  const int h0 = blockIdx.y * 8, w0 = blockIdx.x * 32;
  const int tid = threadIdx.x;
  const int tx = tid & 31, ty = tid >> 5;
  const int h = h0 + ty, w = w0 + tx;

  __shared__ float m_s[4][14][38][4];
  const float* __restrict__ attn = out + ATTN_OFF;

  float acc[16];
#pragma unroll
  for (int i = 0; i < 16; ++i) acc[i] = 0.f;

#pragma unroll 1
  for (int t = 0; t < 4; ++t) {
    float a[49];
#pragma unroll
    for (int d = 0; d < 49; ++d)
      a[d] = attn[((b * 196 + d * 4 + t) << 14) + (h << 7) + w];

    __syncthreads();
    for (int e = tid; e < 8512; e += 256) {
      int c16 = e / 532; int rem = e - c16 * 532;
      int y = rem / 38;  int x = rem - y * 38;
      int gy = h0 - 3 + y, gx = w0 - 3 + x;
      float v = 0.f;
      if (gy >= 0 && gy < 128 && gx >= 0 && gx < 128)
        v = m_out[(((b * 64 + cq * 16 + c16) * 4 + t) << 14) + (gy << 7) + gx];
      m_s[c16 >> 2][y][x][c16 & 3] = v;
    }
    __syncthreads();

#pragma unroll
    for (int dy = 0; dy < 7; ++dy)
#pragma unroll
      for (int dx = 0; dx < 7; ++dx) {
        const float av = a[dy * 7 + dx];
#pragma unroll
        for (int q = 0; q < 4; ++q) {
          const float4 mv = *(const float4*)&m_s[q][ty + dy][tx + dx][0];
          acc[q * 4 + 0] += av * mv.x;
          acc[q * 4 + 1] += av * mv.y;
          acc[q * 4 + 2] += av * mv.z;
          acc[q * 4 + 3] += av * mv.w;
        }
      }
  }

#pragma unroll
  for (int q = 0; q < 4; ++q)
#pragma unroll
    for (int k = 0; k < 4; ++k)
      out[((b * 64 + cq * 16 + q * 4 + k) << 14) + (h << 7) + w] = acc[q * 4 + k];
}

extern "C" void kernel_launch(void* const* d_in, const int* in_sizes, int n_in,
                              void* d_out, int out_size, void* d_ws, size_t ws_size,
                              hipStream_t stream) {
  const float* m_in  = (const float*)d_in[0];
  const float* m_out = (const float*)d_in[1];
  const float* q_in  = (const float*)d_in[2];
  const float* cst   = (const float*)d_in[3];
  float* out = (float*)d_out;

  const bool use_ws = (ws_size >= WS_F4_COUNT * 16ull) && d_ws != nullptr;
  float4* ws = use_ws ? (float4*)d_ws : nullptr;

  k1_corr<<<dim3(4, 8, 16), dim3(256), 0, stream>>>(m_in, q_in, out);
  k2_softmax<<<dim3(1024), dim3(256), 0, stream>>>(out, cst, ws);
  if (use_ws)
    k3_read_ws<<<dim3(4, 16, 16), dim3(256), 0, stream>>>(m_out, out, ws);
  else
    k3_read_fb<<<dim3(4, 16, 16), dim3(256), 0, stream>>>(m_out, out);
}